// Round 4
// baseline (630.459 us; speedup 1.0000x reference)
//
#include <hip/hip_runtime.h>

// ---------------------------------------------------------------------------
// 2-layer GCN, CSR-free: bucketed counting scatter + per-bucket LDS-atomic
// aggregation (zero global atomics, no per-node sort, no gather re-reads).
//   out = dinv * (A (relu((dinv*(A' xs)) W1 + b1) W2 * dinv)) + b2
// xs = x*dinv; self loop folded in as a seed term.
// Buckets: 128 dst nodes each (dst>>7). Edge packed to uint32:
//   word = src | (local_dst << 25)   (requires n_nodes < 2^25)
// ---------------------------------------------------------------------------

#define BKT_BITS 7
#define BKT_SZ   128       // nodes per bucket
#define NBK      1024      // padded bucket slots (>= actual buckets)
#define NBLKA    512       // blocks in histA/scatterA (edge partition)
#define SRC_MASK 0x1FFFFFFu

static __device__ __forceinline__ int get_src(const void* ei, int is64, int n_edges, unsigned e) {
    return is64 ? (int)((const long long*)ei)[e] : ((const int*)ei)[e];
}
static __device__ __forceinline__ int get_dst(const void* ei, int is64, int n_edges, unsigned e) {
    return is64 ? (int)((const long long*)ei)[(unsigned)n_edges + e]
                : ((const int*)ei)[(unsigned)n_edges + e];
}

// Detect whether edge_index arrived as int64 (odd 32-bit words all zero) or int32.
static __global__ void detect64_kernel(const unsigned int* __restrict__ w, int* flag) {
    __shared__ int nz;
    if (threadIdx.x == 0) nz = 0;
    __syncthreads();
    int local = 0;
    for (int k = threadIdx.x; k < 4096; k += blockDim.x)
        if (w[2 * k + 1] != 0u) local = 1;
    if (local) atomicOr(&nz, 1);
    __syncthreads();
    if (threadIdx.x == 0) *flag = (nz == 0) ? 1 : 0;  // 1 => int64 encoding
}

// Per-block LDS histogram over buckets (dst >> BKT_BITS).
static __global__ void histA_kernel(const void* __restrict__ ei, const int* __restrict__ flag,
                                    unsigned* __restrict__ histA, int n_edges) {
    __shared__ unsigned h[NBK];
    for (int i = threadIdx.x; i < NBK; i += 256) h[i] = 0u;
    __syncthreads();
    const int is64 = *flag;
    unsigned stride = gridDim.x * blockDim.x;
    for (unsigned e = blockIdx.x * blockDim.x + threadIdx.x; e < (unsigned)n_edges; e += stride) {
        int d = get_dst(ei, is64, n_edges, e);
        atomicAdd(&h[(unsigned)d >> BKT_BITS], 1u);
    }
    __syncthreads();
    for (int i = threadIdx.x; i < NBK; i += 256)
        histA[blockIdx.x * NBK + i] = h[i];
}

// Per bucket b: exclusive scan of histA[blk][b] over blk=0..NBLKA-1; total[b].
static __global__ void scan1_kernel(unsigned* __restrict__ histA, unsigned* __restrict__ total) {
    __shared__ unsigned s0[NBLKA], s1[NBLKA];
    const int b = blockIdx.x;
    const int t = threadIdx.x;
    unsigned v0 = histA[t * NBK + b];
    unsigned v1 = histA[(t + 256) * NBK + b];
    unsigned* a = s0; unsigned* c = s1;
    a[t] = v0; a[t + 256] = v1;
    __syncthreads();
    for (int off = 1; off < NBLKA; off <<= 1) {
        for (int i = t; i < NBLKA; i += 256)
            c[i] = a[i] + (i >= off ? a[i - off] : 0u);
        __syncthreads();
        unsigned* tmp = a; a = c; c = tmp;
    }
    histA[t * NBK + b] = a[t] - v0;
    histA[(t + 256) * NBK + b] = a[t + 256] - v1;
    if (t == 255) total[b] = a[NBLKA - 1];
}

// Exclusive scan of bucket totals -> bucket_base. One block, NBK threads.
static __global__ void scan2_kernel(const unsigned* __restrict__ total,
                                    unsigned* __restrict__ bucket_base) {
    __shared__ unsigned s0[NBK], s1[NBK];
    const int t = threadIdx.x;
    unsigned v = total[t];
    unsigned* a = s0; unsigned* c = s1;
    a[t] = v;
    __syncthreads();
    for (int off = 1; off < NBK; off <<= 1) {
        c[t] = a[t] + (t >= off ? a[t - off] : 0u);
        __syncthreads();
        unsigned* tmp = a; a = c; c = tmp;
    }
    bucket_base[t] = a[t] - v;
}

// Scatter edges into dst-bucketed order, packed: src | (local_dst << 25).
static __global__ void scatterA_kernel(const void* __restrict__ ei, const int* __restrict__ flag,
                                       const unsigned* __restrict__ histA,
                                       const unsigned* __restrict__ bucket_base,
                                       unsigned* __restrict__ bucketed, int n_edges) {
    __shared__ unsigned cur[NBK];
    for (int i = threadIdx.x; i < NBK; i += 256)
        cur[i] = bucket_base[i] + histA[blockIdx.x * NBK + i];
    __syncthreads();
    const int is64 = *flag;
    unsigned stride = gridDim.x * blockDim.x;
    for (unsigned e = blockIdx.x * blockDim.x + threadIdx.x; e < (unsigned)n_edges; e += stride) {
        unsigned s = (unsigned)get_src(ei, is64, n_edges, e);
        unsigned d = (unsigned)get_dst(ei, is64, n_edges, e);
        unsigned pos = atomicAdd(&cur[d >> BKT_BITS], 1u);
        bucketed[pos] = s | ((d & (BKT_SZ - 1u)) << 25);
    }
}

// Per bucket: LDS degree histogram -> dinv.
static __global__ void degB_kernel(const unsigned* __restrict__ bucketed,
                                   const unsigned* __restrict__ total,
                                   const unsigned* __restrict__ bucket_base,
                                   float* __restrict__ dinv, int n_nodes) {
    const int b = blockIdx.x;
    const int n0 = b << BKT_BITS;
    if (n0 >= n_nodes) return;
    __shared__ unsigned h[BKT_SZ];
    const int t = threadIdx.x;
    if (t < BKT_SZ) h[t] = 0u;
    __syncthreads();
    const unsigned base = bucket_base[b];
    const unsigned count = total[b];
    for (unsigned k = t; k < count; k += 256)
        atomicAdd(&h[bucketed[base + k] >> 25], 1u);
    __syncthreads();
    int n = n0 + t;
    if (t < BKT_SZ && n < n_nodes)
        dinv[n] = rsqrtf((float)(h[t] + 1u));
}

// Per node: xs = x*dinv padded to 12 floats (48B rows -> float4 loads).
static __global__ void node1_kernel(const float* __restrict__ x, const float* __restrict__ dinv,
                                    float* __restrict__ xs, int n_nodes) {
    int i = blockIdx.x * blockDim.x + threadIdx.x;
    if (i >= n_nodes) return;
    float di = dinv[i];
    float v[12];
#pragma unroll
    for (int j = 0; j < 10; j++) v[j] = x[i * 10 + j] * di;
    v[10] = 0.f; v[11] = 0.f;
    float4* xr = (float4*)(xs + (size_t)i * 12);
    xr[0] = make_float4(v[0], v[1], v[2], v[3]);
    xr[1] = make_float4(v[4], v[5], v[6], v[7]);
    xr[2] = make_float4(v[8], v[9], v[10], v[11]);
}

// Layer-1 aggregation (LDS fp32 atomics) + dense 10->16->relu->2, fused.
static __global__ void agg1_kernel(const unsigned* __restrict__ bucketed,
                                   const unsigned* __restrict__ total,
                                   const unsigned* __restrict__ bucket_base,
                                   const float* __restrict__ xs,
                                   const float* __restrict__ dinv,
                                   const float* __restrict__ W1, const float* __restrict__ b1,
                                   const float* __restrict__ W2,
                                   float* __restrict__ gs, int n_nodes) {
    const int b = blockIdx.x;
    const int n0 = b << BKT_BITS;
    if (n0 >= n_nodes) return;
    __shared__ float acc[BKT_SZ * 10];
    __shared__ float sW1[160];
    __shared__ float sb1[16];
    __shared__ float sW2[32];
    const int t = threadIdx.x;
    for (int i = t; i < BKT_SZ * 10; i += 256) acc[i] = 0.f;
    for (int k = t; k < 160; k += 256) sW1[k] = W1[k];
    if (t < 16) sb1[t] = b1[t];
    if (t < 32) sW2[t] = W2[t];
    __syncthreads();
    const unsigned base = bucket_base[b];
    const unsigned count = total[b];
    const float4* X = (const float4*)xs;
    for (unsigned k = t; k < count; k += 256) {
        unsigned w = bucketed[base + k];
        unsigned s = w & SRC_MASK;
        unsigned l = w >> 25;
        float4 v0 = X[s * 3 + 0];
        float4 v1 = X[s * 3 + 1];
        float4 v2 = X[s * 3 + 2];
        float* a = &acc[l * 10];
        atomicAdd(&a[0], v0.x); atomicAdd(&a[1], v0.y);
        atomicAdd(&a[2], v0.z); atomicAdd(&a[3], v0.w);
        atomicAdd(&a[4], v1.x); atomicAdd(&a[5], v1.y);
        atomicAdd(&a[6], v1.z); atomicAdd(&a[7], v1.w);
        atomicAdd(&a[8], v2.x); atomicAdd(&a[9], v2.y);
    }
    __syncthreads();
    int n = n0 + t;
    if (t < BKT_SZ && n < n_nodes) {
        float di = dinv[n];
        const float* xsr = xs + (size_t)n * 12;   // self-loop term
        float a[10];
#pragma unroll
        for (int j = 0; j < 10; j++) a[j] = (acc[t * 10 + j] + xsr[j]) * di;
        float g0 = 0.f, g1 = 0.f;
#pragma unroll
        for (int j = 0; j < 16; j++) {
            float h = sb1[j];
#pragma unroll
            for (int k2 = 0; k2 < 10; k2++) h = fmaf(a[k2], sW1[k2 * 16 + j], h);
            h = fmaxf(h, 0.f);
            g0 = fmaf(h, sW2[j * 2 + 0], g0);
            g1 = fmaf(h, sW2[j * 2 + 1], g1);
        }
        gs[(size_t)n * 2 + 0] = g0 * di;
        gs[(size_t)n * 2 + 1] = g1 * di;
    }
}

// Layer-2 aggregation (LDS fp32 atomics) + self + dinv scale + bias, fused.
static __global__ void agg2_kernel(const unsigned* __restrict__ bucketed,
                                   const unsigned* __restrict__ total,
                                   const unsigned* __restrict__ bucket_base,
                                   const float* __restrict__ gs,
                                   const float* __restrict__ dinv,
                                   const float* __restrict__ b2,
                                   float* __restrict__ out, int n_nodes) {
    const int b = blockIdx.x;
    const int n0 = b << BKT_BITS;
    if (n0 >= n_nodes) return;
    __shared__ float acc[BKT_SZ * 2];
    const int t = threadIdx.x;
    if (t < BKT_SZ * 2) acc[t] = 0.f;
    __syncthreads();
    const unsigned base = bucket_base[b];
    const unsigned count = total[b];
    const float2* G = (const float2*)gs;
    for (unsigned k = t; k < count; k += 256) {
        unsigned w = bucketed[base + k];
        unsigned s = w & SRC_MASK;
        unsigned l = w >> 25;
        float2 v = G[s];
        atomicAdd(&acc[l * 2 + 0], v.x);
        atomicAdd(&acc[l * 2 + 1], v.y);
    }
    __syncthreads();
    int n = n0 + t;
    if (t < BKT_SZ && n < n_nodes) {
        float2 self = G[n];
        float di = dinv[n];
        float2 o;
        o.x = fmaf(acc[t * 2 + 0] + self.x, di, b2[0]);
        o.y = fmaf(acc[t * 2 + 1] + self.y, di, b2[1]);
        ((float2*)out)[n] = o;
    }
}

// ---------------- fallback (atomic-CSR + wave gathers, proven path) --------
static __global__ void deg_kernel(const void* __restrict__ ei, const int* __restrict__ flag,
                                  unsigned int* __restrict__ cnt, int n_edges) {
    const int is64 = *flag;
    unsigned stride = gridDim.x * blockDim.x;
    for (unsigned e = blockIdx.x * blockDim.x + threadIdx.x; e < (unsigned)n_edges; e += stride) {
        int d = get_dst(ei, is64, n_edges, e);
        atomicAdd(&cnt[d], 1u);
    }
}
static __global__ void alloc_kernel(const unsigned int* __restrict__ cnt,
                                    unsigned int* __restrict__ row_start,
                                    unsigned int* __restrict__ cursor,
                                    unsigned int* __restrict__ gcur,
                                    float* __restrict__ dinv, int n_nodes) {
    __shared__ unsigned wsum[4];
    int i = blockIdx.x * blockDim.x + threadIdx.x;
    int lane = threadIdx.x & 63;
    int wid = threadIdx.x >> 6;
    unsigned d = (i < n_nodes) ? cnt[i] : 0u;
    unsigned scan = d;
#pragma unroll
    for (int off = 1; off < 64; off <<= 1) {
        unsigned t = __shfl_up(scan, off);
        if (lane >= off) scan += t;
    }
    if (lane == 63) wsum[wid] = scan;
    __syncthreads();
    if (threadIdx.x == 0) {
        unsigned s0 = wsum[0], s1 = wsum[1], s2 = wsum[2], s3 = wsum[3];
        unsigned base = atomicAdd(gcur, s0 + s1 + s2 + s3);
        wsum[0] = base;
        wsum[1] = base + s0;
        wsum[2] = base + s0 + s1;
        wsum[3] = base + s0 + s1 + s2;
    }
    __syncthreads();
    if (i < n_nodes) {
        unsigned pos = wsum[wid] + scan - d;
        row_start[i] = pos;
        cursor[i] = pos;
        dinv[i] = rsqrtf((float)(d + 1u));
    }
}
static __global__ void csrfill_kernel(const void* __restrict__ ei, const int* __restrict__ flag,
                                      unsigned int* __restrict__ cursor,
                                      unsigned int* __restrict__ csr_src, int n_edges) {
    const int is64 = *flag;
    unsigned stride = gridDim.x * blockDim.x;
    for (unsigned e = blockIdx.x * blockDim.x + threadIdx.x; e < (unsigned)n_edges; e += stride) {
        int s = get_src(ei, is64, n_edges, e);
        int d = get_dst(ei, is64, n_edges, e);
        unsigned pos = atomicAdd(&cursor[d], 1u);
        csr_src[pos] = (unsigned)s;
    }
}
static __global__ void gather1_kernel(const unsigned int* __restrict__ row_start,
                                      const unsigned int* __restrict__ cnt,
                                      const unsigned int* __restrict__ csr_src,
                                      const float* __restrict__ xs,
                                      float* __restrict__ accx, int n_nodes) {
    int w = blockIdx.x * (blockDim.x >> 6) + (threadIdx.x >> 6);
    int lane = threadIdx.x & 63;
    if (w >= n_nodes) return;
    unsigned start = row_start[w];
    unsigned degn = cnt[w];
    float acc[10];
#pragma unroll
    for (int j = 0; j < 10; j++) acc[j] = 0.f;
    const float4* X = (const float4*)xs;
    for (unsigned k = lane; k < degn; k += 64) {
        unsigned s = csr_src[start + k];
        float4 v0 = X[s * 3 + 0];
        float4 v1 = X[s * 3 + 1];
        float4 v2 = X[s * 3 + 2];
        acc[0] += v0.x; acc[1] += v0.y; acc[2] += v0.z; acc[3] += v0.w;
        acc[4] += v1.x; acc[5] += v1.y; acc[6] += v1.z; acc[7] += v1.w;
        acc[8] += v2.x; acc[9] += v2.y;
    }
#pragma unroll
    for (int off = 32; off > 0; off >>= 1) {
#pragma unroll
        for (int j = 0; j < 10; j++) acc[j] += __shfl_down(acc[j], off);
    }
    if (lane == 0) {
        const float* xsr = xs + (size_t)w * 12;
        float4* A = (float4*)(accx + (size_t)w * 12);
        A[0] = make_float4(acc[0] + xsr[0], acc[1] + xsr[1], acc[2] + xsr[2], acc[3] + xsr[3]);
        A[1] = make_float4(acc[4] + xsr[4], acc[5] + xsr[5], acc[6] + xsr[6], acc[7] + xsr[7]);
        A[2] = make_float4(acc[8] + xsr[8], acc[9] + xsr[9], 0.f, 0.f);
    }
}
static __global__ void node2_kernel(const float* __restrict__ accx, const float* __restrict__ dinv,
                                    const float* __restrict__ W1, const float* __restrict__ b1,
                                    const float* __restrict__ W2,
                                    float* __restrict__ gs, int n_nodes) {
    __shared__ float sW1[160];
    __shared__ float sb1[16];
    __shared__ float sW2[32];
    for (int k = threadIdx.x; k < 160; k += blockDim.x) sW1[k] = W1[k];
    if (threadIdx.x < 16) sb1[threadIdx.x] = b1[threadIdx.x];
    if (threadIdx.x < 32) sW2[threadIdx.x] = W2[threadIdx.x];
    __syncthreads();
    int i = blockIdx.x * blockDim.x + threadIdx.x;
    if (i >= n_nodes) return;
    float di = dinv[i];
    float a[10];
#pragma unroll
    for (int k = 0; k < 10; k++) a[k] = accx[(size_t)i * 12 + k] * di;
    float g0 = 0.f, g1 = 0.f;
#pragma unroll
    for (int j = 0; j < 16; j++) {
        float h = sb1[j];
#pragma unroll
        for (int k = 0; k < 10; k++) h = fmaf(a[k], sW1[k * 16 + j], h);
        h = fmaxf(h, 0.f);
        g0 = fmaf(h, sW2[j * 2 + 0], g0);
        g1 = fmaf(h, sW2[j * 2 + 1], g1);
    }
    gs[(size_t)i * 2 + 0] = g0 * di;
    gs[(size_t)i * 2 + 1] = g1 * di;
}
static __global__ void gather2_kernel(const unsigned int* __restrict__ row_start,
                                      const unsigned int* __restrict__ cnt,
                                      const unsigned int* __restrict__ csr_src,
                                      const float* __restrict__ gs,
                                      const float* __restrict__ dinv,
                                      const float* __restrict__ b2,
                                      float* __restrict__ out, int n_nodes) {
    int w = blockIdx.x * (blockDim.x >> 6) + (threadIdx.x >> 6);
    int lane = threadIdx.x & 63;
    if (w >= n_nodes) return;
    unsigned start = row_start[w];
    unsigned degn = cnt[w];
    float a0 = 0.f, a1 = 0.f;
    const float2* G = (const float2*)gs;
    for (unsigned k = lane; k < degn; k += 64) {
        unsigned s = csr_src[start + k];
        float2 v = G[s];
        a0 += v.x; a1 += v.y;
    }
#pragma unroll
    for (int off = 32; off > 0; off >>= 1) {
        a0 += __shfl_down(a0, off);
        a1 += __shfl_down(a1, off);
    }
    if (lane == 0) {
        float2 self = G[w];
        float di = dinv[w];
        float2 o;
        o.x = fmaf(a0 + self.x, di, b2[0]);
        o.y = fmaf(a1 + self.y, di, b2[1]);
        ((float2*)out)[w] = o;
    }
}

extern "C" void kernel_launch(void* const* d_in, const int* in_sizes, int n_in,
                              void* d_out, int out_size, void* d_ws, size_t ws_size,
                              hipStream_t stream) {
    const float* x  = (const float*)d_in[0];
    const void*  ei = d_in[1];
    const float* W1 = (const float*)d_in[2];
    const float* b1 = (const float*)d_in[3];
    const float* W2 = (const float*)d_in[4];
    const float* b2 = (const float*)d_in[5];
    float* out = (float*)d_out;

    const int n_nodes = in_sizes[0] / 10;
    const int n_edges = in_sizes[1] / 2;
    (void)n_in; (void)out_size;

    const int nbuckets = (n_nodes + BKT_SZ - 1) >> BKT_BITS;
    const bool pack_ok = (n_nodes <= (1 << 25)) && (nbuckets <= NBK);

    char* p = (char*)d_ws;
    int* flag = (int*)p;
    unsigned* gcur = (unsigned*)(p + 64);
    p += 256;

    const size_t need_new = 256 + (size_t)NBLKA * NBK * 4 + 2 * (size_t)NBK * 4 + 64 +
                            (size_t)n_nodes * (4 + 8 + 48) + (size_t)n_edges * 4;

    if (pack_ok && ws_size >= need_new) {
        unsigned* histA = (unsigned*)p;       p += (size_t)NBLKA * NBK * 4;
        unsigned* total = (unsigned*)p;       p += (size_t)NBK * 4;
        unsigned* bucket_base = (unsigned*)p; p += (size_t)NBK * 4 + 64;
        float* dinv = (float*)p;              p += (size_t)n_nodes * 4;
        float* gs = (float*)p;                p += (size_t)n_nodes * 8;
        float* xs = (float*)p;                p += (size_t)n_nodes * 48;
        unsigned* bucketed = (unsigned*)p;    p += (size_t)n_edges * 4;

        detect64_kernel<<<1, 256, 0, stream>>>((const unsigned int*)ei, flag);
        histA_kernel<<<NBLKA, 256, 0, stream>>>(ei, flag, histA, n_edges);
        scan1_kernel<<<NBK, 256, 0, stream>>>(histA, total);
        scan2_kernel<<<1, NBK, 0, stream>>>(total, bucket_base);
        scatterA_kernel<<<NBLKA, 256, 0, stream>>>(ei, flag, histA, bucket_base, bucketed, n_edges);
        degB_kernel<<<nbuckets, 256, 0, stream>>>(bucketed, total, bucket_base, dinv, n_nodes);
        node1_kernel<<<(n_nodes + 255) / 256, 256, 0, stream>>>(x, dinv, xs, n_nodes);
        agg1_kernel<<<nbuckets, 256, 0, stream>>>(bucketed, total, bucket_base, xs, dinv,
                                                  W1, b1, W2, gs, n_nodes);
        agg2_kernel<<<nbuckets, 256, 0, stream>>>(bucketed, total, bucket_base, gs, dinv, b2,
                                                  out, n_nodes);
    } else {
        // fallback: atomic CSR + wave gathers
        unsigned* row_start = (unsigned*)p; p += (size_t)n_nodes * 4;
        unsigned* cnt = (unsigned*)p;       p += (size_t)n_nodes * 4;
        float* dinv = (float*)p;            p += (size_t)n_nodes * 4;
        float* gs = (float*)p;              p += (size_t)n_nodes * 8;
        float* xs = (float*)p;              p += (size_t)n_nodes * 48;
        float* accx = (float*)p;            p += (size_t)n_nodes * 48;
        unsigned* csr_src = (unsigned*)p;   p += (size_t)n_edges * 4;
        unsigned* cursor = (unsigned*)p;    p += (size_t)n_nodes * 4;

        hipMemsetAsync(d_ws, 0, 256, stream);
        hipMemsetAsync(cnt, 0, (size_t)n_nodes * 4, stream);
        detect64_kernel<<<1, 256, 0, stream>>>((const unsigned int*)ei, flag);
        deg_kernel<<<2048, 256, 0, stream>>>(ei, flag, cnt, n_edges);
        alloc_kernel<<<(n_nodes + 255) / 256, 256, 0, stream>>>(cnt, row_start, cursor, gcur, dinv, n_nodes);
        csrfill_kernel<<<4096, 256, 0, stream>>>(ei, flag, cursor, csr_src, n_edges);
        node1_kernel<<<(n_nodes + 255) / 256, 256, 0, stream>>>(x, dinv, xs, n_nodes);
        gather1_kernel<<<(n_nodes + 3) / 4, 256, 0, stream>>>(row_start, cnt, csr_src, xs, accx, n_nodes);
        node2_kernel<<<(n_nodes + 255) / 256, 256, 0, stream>>>(accx, dinv, W1, b1, W2, gs, n_nodes);
        gather2_kernel<<<(n_nodes + 3) / 4, 256, 0, stream>>>(row_start, cnt, csr_src, gs, dinv, b2, out, n_nodes);
    }
}

// Round 5
// 272.879 us; speedup vs baseline: 2.3104x; 2.3104x over previous
//
#include <hip/hip_runtime.h>

// ---------------------------------------------------------------------------
// 2-layer GCN: atomic-free CSR build (bucketed counting sort, 128-node
// buckets) + register-accumulating wave gathers (R3 structure, passB fixed).
//   out = dinv * (A (relu((dinv*(A' xs)) W1 + b1) W2 * dinv)) + b2
// xs = x*dinv; self loop folded in as a seed term.
// Edge packed to uint32: word = src | (local_dst << 25)  (n_nodes < 2^25).
// ---------------------------------------------------------------------------

#define BKT_BITS 7
#define BKT_SZ   128       // nodes per bucket
#define NBK      1024      // padded bucket slots (power of 2, >= n buckets)
#define NBLKA    512       // blocks in histA/scatterA (edge partition)
#define SRC_MASK 0x1FFFFFFu

static __device__ __forceinline__ int get_src(const void* ei, int is64, int n_edges, unsigned e) {
    return is64 ? (int)((const long long*)ei)[e] : ((const int*)ei)[e];
}
static __device__ __forceinline__ int get_dst(const void* ei, int is64, int n_edges, unsigned e) {
    return is64 ? (int)((const long long*)ei)[(unsigned)n_edges + e]
                : ((const int*)ei)[(unsigned)n_edges + e];
}

// Detect whether edge_index arrived as int64 (odd 32-bit words all zero) or int32.
static __global__ void detect64_kernel(const unsigned int* __restrict__ w, int* flag) {
    __shared__ int nz;
    if (threadIdx.x == 0) nz = 0;
    __syncthreads();
    int local = 0;
    for (int k = threadIdx.x; k < 4096; k += blockDim.x)
        if (w[2 * k + 1] != 0u) local = 1;
    if (local) atomicOr(&nz, 1);
    __syncthreads();
    if (threadIdx.x == 0) *flag = (nz == 0) ? 1 : 0;  // 1 => int64 encoding
}

// Per-block LDS histogram over buckets (dst >> BKT_BITS).
static __global__ void histA_kernel(const void* __restrict__ ei, const int* __restrict__ flag,
                                    unsigned* __restrict__ histA, int n_edges) {
    __shared__ unsigned h[NBK];
    for (int i = threadIdx.x; i < NBK; i += 256) h[i] = 0u;
    __syncthreads();
    const int is64 = *flag;
    unsigned stride = gridDim.x * blockDim.x;
    for (unsigned e = blockIdx.x * blockDim.x + threadIdx.x; e < (unsigned)n_edges; e += stride) {
        int d = get_dst(ei, is64, n_edges, e);
        atomicAdd(&h[(unsigned)d >> BKT_BITS], 1u);
    }
    __syncthreads();
    for (int i = threadIdx.x; i < NBK; i += 256)
        histA[blockIdx.x * NBK + i] = h[i];
}

// Per bucket b: exclusive scan of histA[blk][b] over blk=0..NBLKA-1; total[b].
static __global__ void scan1_kernel(unsigned* __restrict__ histA, unsigned* __restrict__ total) {
    __shared__ unsigned s0[NBLKA], s1[NBLKA];
    const int b = blockIdx.x;
    const int t = threadIdx.x;
    unsigned v0 = histA[t * NBK + b];
    unsigned v1 = histA[(t + 256) * NBK + b];
    unsigned* a = s0; unsigned* c = s1;
    a[t] = v0; a[t + 256] = v1;
    __syncthreads();
    for (int off = 1; off < NBLKA; off <<= 1) {
        for (int i = t; i < NBLKA; i += 256)
            c[i] = a[i] + (i >= off ? a[i - off] : 0u);
        __syncthreads();
        unsigned* tmp = a; a = c; c = tmp;
    }
    histA[t * NBK + b] = a[t] - v0;
    histA[(t + 256) * NBK + b] = a[t + 256] - v1;
    if (t == 255) total[b] = a[NBLKA - 1];
}

// Exclusive scan of bucket totals -> bucket_base. One block, NBK threads.
static __global__ void scan2_kernel(const unsigned* __restrict__ total,
                                    unsigned* __restrict__ bucket_base) {
    __shared__ unsigned s0[NBK], s1[NBK];
    const int t = threadIdx.x;
    unsigned v = total[t];
    unsigned* a = s0; unsigned* c = s1;
    a[t] = v;
    __syncthreads();
    for (int off = 1; off < NBK; off <<= 1) {
        c[t] = a[t] + (t >= off ? a[t - off] : 0u);
        __syncthreads();
        unsigned* tmp = a; a = c; c = tmp;
    }
    bucket_base[t] = a[t] - v;
}

// Scatter edges into dst-bucketed order, packed: src | (local_dst << 25).
static __global__ void scatterA_kernel(const void* __restrict__ ei, const int* __restrict__ flag,
                                       const unsigned* __restrict__ histA,
                                       const unsigned* __restrict__ bucket_base,
                                       unsigned* __restrict__ bucketed, int n_edges) {
    __shared__ unsigned cur[NBK];
    for (int i = threadIdx.x; i < NBK; i += 256)
        cur[i] = bucket_base[i] + histA[blockIdx.x * NBK + i];
    __syncthreads();
    const int is64 = *flag;
    unsigned stride = gridDim.x * blockDim.x;
    for (unsigned e = blockIdx.x * blockDim.x + threadIdx.x; e < (unsigned)n_edges; e += stride) {
        unsigned s = (unsigned)get_src(ei, is64, n_edges, e);
        unsigned d = (unsigned)get_dst(ei, is64, n_edges, e);
        unsigned pos = atomicAdd(&cur[d >> BKT_BITS], 1u);
        bucketed[pos] = s | ((d & (BKT_SZ - 1u)) << 25);
    }
}

// Per 128-node bucket: counting sort by local dst; emit csr_src, row_start,
// cnt, dinv. 782 blocks -> good occupancy (passB's 7.4% fixed).
static __global__ void passB_kernel(const unsigned* __restrict__ bucketed,
                                    const unsigned* __restrict__ total,
                                    const unsigned* __restrict__ bucket_base,
                                    unsigned* __restrict__ csr_src,
                                    unsigned* __restrict__ row_start,
                                    unsigned* __restrict__ cnt,
                                    float* __restrict__ dinv, int n_nodes) {
    const int b = blockIdx.x;
    const int n0 = b << BKT_BITS;
    if (n0 >= n_nodes) return;
    const int t = threadIdx.x;
    const unsigned base = bucket_base[b];
    const unsigned count = total[b];

    __shared__ unsigned h[BKT_SZ];
    __shared__ unsigned s0[BKT_SZ], s1[BKT_SZ];
    __shared__ unsigned cur[BKT_SZ];
    if (t < BKT_SZ) h[t] = 0u;
    __syncthreads();
    for (unsigned k = t; k < count; k += 256)
        atomicAdd(&h[bucketed[base + k] >> 25], 1u);
    __syncthreads();
    unsigned* a = s0; unsigned* c = s1;
    if (t < BKT_SZ) a[t] = h[t];
    __syncthreads();
    for (int off = 1; off < BKT_SZ; off <<= 1) {
        if (t < BKT_SZ) c[t] = a[t] + (t >= off ? a[t - off] : 0u);
        __syncthreads();
        unsigned* tmp = a; a = c; c = tmp;
    }
    // a = inclusive scan; exclusive = a[t]-h[t]
    if (t < BKT_SZ) {
        unsigned excl = a[t] - h[t];
        cur[t] = excl;
        int n = n0 + t;
        if (n < n_nodes) {
            row_start[n] = base + excl;
            cnt[n] = h[t];
            dinv[n] = rsqrtf((float)(h[t] + 1u));
        }
    }
    __syncthreads();
    for (unsigned k = t; k < count; k += 256) {
        unsigned w = bucketed[base + k];
        unsigned pos = base + atomicAdd(&cur[w >> 25], 1u);
        csr_src[pos] = w & SRC_MASK;
    }
}

// Per node: xs = x*dinv padded to 12 floats (48B rows -> float4 loads).
static __global__ void node1_kernel(const float* __restrict__ x, const float* __restrict__ dinv,
                                    float* __restrict__ xs, int n_nodes) {
    int i = blockIdx.x * blockDim.x + threadIdx.x;
    if (i >= n_nodes) return;
    float di = dinv[i];
    float v[12];
#pragma unroll
    for (int j = 0; j < 10; j++) v[j] = x[i * 10 + j] * di;
    v[10] = 0.f; v[11] = 0.f;
    float4* xr = (float4*)(xs + (size_t)i * 12);
    xr[0] = make_float4(v[0], v[1], v[2], v[3]);
    xr[1] = make_float4(v[4], v[5], v[6], v[7]);
    xr[2] = make_float4(v[8], v[9], v[10], v[11]);
}

// Layer-1 gather: one wave per node, lanes stride the CSR row, register acc.
static __global__ void gather1_kernel(const unsigned int* __restrict__ row_start,
                                      const unsigned int* __restrict__ cnt,
                                      const unsigned int* __restrict__ csr_src,
                                      const float* __restrict__ xs,
                                      float* __restrict__ accx, int n_nodes) {
    int w = blockIdx.x * (blockDim.x >> 6) + (threadIdx.x >> 6);
    int lane = threadIdx.x & 63;
    if (w >= n_nodes) return;
    unsigned start = row_start[w];
    unsigned degn = cnt[w];
    float acc[10];
#pragma unroll
    for (int j = 0; j < 10; j++) acc[j] = 0.f;
    const float4* X = (const float4*)xs;
    for (unsigned k = lane; k < degn; k += 64) {
        unsigned s = csr_src[start + k];
        float4 v0 = X[s * 3 + 0];
        float4 v1 = X[s * 3 + 1];
        float4 v2 = X[s * 3 + 2];
        acc[0] += v0.x; acc[1] += v0.y; acc[2] += v0.z; acc[3] += v0.w;
        acc[4] += v1.x; acc[5] += v1.y; acc[6] += v1.z; acc[7] += v1.w;
        acc[8] += v2.x; acc[9] += v2.y;
    }
#pragma unroll
    for (int off = 32; off > 0; off >>= 1) {
#pragma unroll
        for (int j = 0; j < 10; j++) acc[j] += __shfl_down(acc[j], off);
    }
    if (lane == 0) {
        const float* xsr = xs + (size_t)w * 12;   // self-loop contribution
        float4* A = (float4*)(accx + (size_t)w * 12);
        A[0] = make_float4(acc[0] + xsr[0], acc[1] + xsr[1], acc[2] + xsr[2], acc[3] + xsr[3]);
        A[1] = make_float4(acc[4] + xsr[4], acc[5] + xsr[5], acc[6] + xsr[6], acc[7] + xsr[7]);
        A[2] = make_float4(acc[8] + xsr[8], acc[9] + xsr[9], 0.f, 0.f);
    }
}

// Per node: h1 = (dinv*accx)@W1 + b1, relu, g = h1@W2, gs = g*dinv.
static __global__ void node2_kernel(const float* __restrict__ accx, const float* __restrict__ dinv,
                                    const float* __restrict__ W1, const float* __restrict__ b1,
                                    const float* __restrict__ W2,
                                    float* __restrict__ gs, int n_nodes) {
    __shared__ float sW1[160];
    __shared__ float sb1[16];
    __shared__ float sW2[32];
    for (int k = threadIdx.x; k < 160; k += blockDim.x) sW1[k] = W1[k];
    if (threadIdx.x < 16) sb1[threadIdx.x] = b1[threadIdx.x];
    if (threadIdx.x < 32) sW2[threadIdx.x] = W2[threadIdx.x];
    __syncthreads();
    int i = blockIdx.x * blockDim.x + threadIdx.x;
    if (i >= n_nodes) return;
    float di = dinv[i];
    float a[10];
#pragma unroll
    for (int k = 0; k < 10; k++) a[k] = accx[(size_t)i * 12 + k] * di;
    float g0 = 0.f, g1 = 0.f;
#pragma unroll
    for (int j = 0; j < 16; j++) {
        float h = sb1[j];
#pragma unroll
        for (int k = 0; k < 10; k++) h = fmaf(a[k], sW1[k * 16 + j], h);
        h = fmaxf(h, 0.f);
        g0 = fmaf(h, sW2[j * 2 + 0], g0);
        g1 = fmaf(h, sW2[j * 2 + 1], g1);
    }
    gs[(size_t)i * 2 + 0] = g0 * di;
    gs[(size_t)i * 2 + 1] = g1 * di;
}

// Layer-2 gather + final scale + bias, fused.
static __global__ void gather2_kernel(const unsigned int* __restrict__ row_start,
                                      const unsigned int* __restrict__ cnt,
                                      const unsigned int* __restrict__ csr_src,
                                      const float* __restrict__ gs,
                                      const float* __restrict__ dinv,
                                      const float* __restrict__ b2,
                                      float* __restrict__ out, int n_nodes) {
    int w = blockIdx.x * (blockDim.x >> 6) + (threadIdx.x >> 6);
    int lane = threadIdx.x & 63;
    if (w >= n_nodes) return;
    unsigned start = row_start[w];
    unsigned degn = cnt[w];
    float a0 = 0.f, a1 = 0.f;
    const float2* G = (const float2*)gs;
    for (unsigned k = lane; k < degn; k += 64) {
        unsigned s = csr_src[start + k];
        float2 v = G[s];
        a0 += v.x; a1 += v.y;
    }
#pragma unroll
    for (int off = 32; off > 0; off >>= 1) {
        a0 += __shfl_down(a0, off);
        a1 += __shfl_down(a1, off);
    }
    if (lane == 0) {
        float2 self = G[w];
        float di = dinv[w];
        float2 o;
        o.x = fmaf(a0 + self.x, di, b2[0]);
        o.y = fmaf(a1 + self.y, di, b2[1]);
        ((float2*)out)[w] = o;
    }
}

// ---------------- fallback (atomic-CSR + wave gathers) ---------------------
static __global__ void deg_kernel(const void* __restrict__ ei, const int* __restrict__ flag,
                                  unsigned int* __restrict__ cnt, int n_edges) {
    const int is64 = *flag;
    unsigned stride = gridDim.x * blockDim.x;
    for (unsigned e = blockIdx.x * blockDim.x + threadIdx.x; e < (unsigned)n_edges; e += stride) {
        int d = get_dst(ei, is64, n_edges, e);
        atomicAdd(&cnt[d], 1u);
    }
}
static __global__ void alloc_kernel(const unsigned int* __restrict__ cnt,
                                    unsigned int* __restrict__ row_start,
                                    unsigned int* __restrict__ cursor,
                                    unsigned int* __restrict__ gcur,
                                    float* __restrict__ dinv, int n_nodes) {
    __shared__ unsigned wsum[4];
    int i = blockIdx.x * blockDim.x + threadIdx.x;
    int lane = threadIdx.x & 63;
    int wid = threadIdx.x >> 6;
    unsigned d = (i < n_nodes) ? cnt[i] : 0u;
    unsigned scan = d;
#pragma unroll
    for (int off = 1; off < 64; off <<= 1) {
        unsigned t = __shfl_up(scan, off);
        if (lane >= off) scan += t;
    }
    if (lane == 63) wsum[wid] = scan;
    __syncthreads();
    if (threadIdx.x == 0) {
        unsigned s0 = wsum[0], s1 = wsum[1], s2 = wsum[2], s3 = wsum[3];
        unsigned base = atomicAdd(gcur, s0 + s1 + s2 + s3);
        wsum[0] = base;
        wsum[1] = base + s0;
        wsum[2] = base + s0 + s1;
        wsum[3] = base + s0 + s1 + s2;
    }
    __syncthreads();
    if (i < n_nodes) {
        unsigned pos = wsum[wid] + scan - d;
        row_start[i] = pos;
        cursor[i] = pos;
        dinv[i] = rsqrtf((float)(d + 1u));
    }
}
static __global__ void csrfill_kernel(const void* __restrict__ ei, const int* __restrict__ flag,
                                      unsigned int* __restrict__ cursor,
                                      unsigned int* __restrict__ csr_src, int n_edges) {
    const int is64 = *flag;
    unsigned stride = gridDim.x * blockDim.x;
    for (unsigned e = blockIdx.x * blockDim.x + threadIdx.x; e < (unsigned)n_edges; e += stride) {
        int s = get_src(ei, is64, n_edges, e);
        int d = get_dst(ei, is64, n_edges, e);
        unsigned pos = atomicAdd(&cursor[d], 1u);
        csr_src[pos] = (unsigned)s;
    }
}

extern "C" void kernel_launch(void* const* d_in, const int* in_sizes, int n_in,
                              void* d_out, int out_size, void* d_ws, size_t ws_size,
                              hipStream_t stream) {
    const float* x  = (const float*)d_in[0];
    const void*  ei = d_in[1];
    const float* W1 = (const float*)d_in[2];
    const float* b1 = (const float*)d_in[3];
    const float* W2 = (const float*)d_in[4];
    const float* b2 = (const float*)d_in[5];
    float* out = (float*)d_out;

    const int n_nodes = in_sizes[0] / 10;
    const int n_edges = in_sizes[1] / 2;
    (void)n_in; (void)out_size;

    const int nbuckets = (n_nodes + BKT_SZ - 1) >> BKT_BITS;
    const bool pack_ok = (n_nodes <= (1 << 25)) && (nbuckets <= NBK);

    char* p = (char*)d_ws;
    int* flag = (int*)p;
    unsigned* gcur = (unsigned*)(p + 64);
    p += 256;
    // common node buffers
    unsigned* row_start = (unsigned*)p; p += (size_t)n_nodes * 4;
    unsigned* cnt = (unsigned*)p;       p += (size_t)n_nodes * 4;
    float* dinv = (float*)p;            p += (size_t)n_nodes * 4;
    float* gs = (float*)p;              p += (size_t)n_nodes * 8;
    float* xs = (float*)p;              p += (size_t)n_nodes * 48;
    float* accx = (float*)p;            p += (size_t)n_nodes * 48;
    unsigned* csr_src = (unsigned*)p;   p += (size_t)n_edges * 4;

    const size_t base_bytes = (size_t)(p - (char*)d_ws);
    const size_t need_new = base_bytes + (size_t)NBLKA * NBK * 4 + 2 * (size_t)NBK * 4 + 64 +
                            (size_t)n_edges * 4;
    const size_t need_old = base_bytes + (size_t)n_nodes * 4;

    if (pack_ok && ws_size >= need_new) {
        unsigned* histA = (unsigned*)p;       p += (size_t)NBLKA * NBK * 4;
        unsigned* total = (unsigned*)p;       p += (size_t)NBK * 4;
        unsigned* bucket_base = (unsigned*)p; p += (size_t)NBK * 4 + 64;
        unsigned* bucketed = (unsigned*)p;    p += (size_t)n_edges * 4;

        detect64_kernel<<<1, 256, 0, stream>>>((const unsigned int*)ei, flag);
        histA_kernel<<<NBLKA, 256, 0, stream>>>(ei, flag, histA, n_edges);
        scan1_kernel<<<NBK, 256, 0, stream>>>(histA, total);
        scan2_kernel<<<1, NBK, 0, stream>>>(total, bucket_base);
        scatterA_kernel<<<NBLKA, 256, 0, stream>>>(ei, flag, histA, bucket_base, bucketed, n_edges);
        passB_kernel<<<nbuckets, 256, 0, stream>>>(bucketed, total, bucket_base, csr_src,
                                                   row_start, cnt, dinv, n_nodes);
        node1_kernel<<<(n_nodes + 255) / 256, 256, 0, stream>>>(x, dinv, xs, n_nodes);
        gather1_kernel<<<(n_nodes + 3) / 4, 256, 0, stream>>>(row_start, cnt, csr_src, xs, accx, n_nodes);
        node2_kernel<<<(n_nodes + 255) / 256, 256, 0, stream>>>(accx, dinv, W1, b1, W2, gs, n_nodes);
        gather2_kernel<<<(n_nodes + 3) / 4, 256, 0, stream>>>(row_start, cnt, csr_src, gs, dinv, b2, out, n_nodes);
    } else if (ws_size >= need_old) {
        unsigned* cursor = (unsigned*)p; p += (size_t)n_nodes * 4;

        hipMemsetAsync(d_ws, 0, 256, stream);
        hipMemsetAsync(cnt, 0, (size_t)n_nodes * 4, stream);
        detect64_kernel<<<1, 256, 0, stream>>>((const unsigned int*)ei, flag);
        deg_kernel<<<2048, 256, 0, stream>>>(ei, flag, cnt, n_edges);
        alloc_kernel<<<(n_nodes + 255) / 256, 256, 0, stream>>>(cnt, row_start, cursor, gcur, dinv, n_nodes);
        csrfill_kernel<<<4096, 256, 0, stream>>>(ei, flag, cursor, csr_src, n_edges);
        node1_kernel<<<(n_nodes + 255) / 256, 256, 0, stream>>>(x, dinv, xs, n_nodes);
        gather1_kernel<<<(n_nodes + 3) / 4, 256, 0, stream>>>(row_start, cnt, csr_src, xs, accx, n_nodes);
        node2_kernel<<<(n_nodes + 255) / 256, 256, 0, stream>>>(accx, dinv, W1, b1, W2, gs, n_nodes);
        gather2_kernel<<<(n_nodes + 3) / 4, 256, 0, stream>>>(row_start, cnt, csr_src, gs, dinv, b2, out, n_nodes);
    }
}

// Round 6
// 242.425 us; speedup vs baseline: 2.6006x; 1.1256x over previous
//
#include <hip/hip_runtime.h>

// ---------------------------------------------------------------------------
// 2-layer GCN: atomic-free CSR build (bucketed counting sort, 256-node
// buckets) + register-accumulating wave gathers with fused dense layers.
//   out = dinv * (A (relu((dinv*(A' xs)) W1 + b1) W2 * dinv)) + b2
// xs = x*dinv; self loop folded in as a seed term.
// Edge packed to uint32: word = src | (local_dst << 24)  (n_nodes < 2^24).
// scatterA locality: 256 blocks x 391 buckets -> 256B runs, 0.8MB/XCD active
// write lines (fits L2), vs R5's 64B runs / 3.2MB/XCD (6x write amplif.).
// ---------------------------------------------------------------------------

#define BKT_BITS  8
#define BKT_SZ    256       // nodes per bucket
#define NBK       512       // padded bucket slots (power of 2, >= n buckets)
#define NBLKA     256       // blocks in histA/scatterA (edge partition)
#define TPB_A     1024      // threads per block in histA/scatterA
#define DST_SHIFT 24
#define SRC_MASK  0xFFFFFFu

static __device__ __forceinline__ int get_src(const void* ei, int is64, int n_edges, unsigned e) {
    return is64 ? (int)((const long long*)ei)[e] : ((const int*)ei)[e];
}
static __device__ __forceinline__ int get_dst(const void* ei, int is64, int n_edges, unsigned e) {
    return is64 ? (int)((const long long*)ei)[(unsigned)n_edges + e]
                : ((const int*)ei)[(unsigned)n_edges + e];
}

// Detect whether edge_index arrived as int64 (odd 32-bit words all zero) or int32.
static __global__ void detect64_kernel(const unsigned int* __restrict__ w, int* flag) {
    __shared__ int nz;
    if (threadIdx.x == 0) nz = 0;
    __syncthreads();
    int local = 0;
    for (int k = threadIdx.x; k < 4096; k += blockDim.x)
        if (w[2 * k + 1] != 0u) local = 1;
    if (local) atomicOr(&nz, 1);
    __syncthreads();
    if (threadIdx.x == 0) *flag = (nz == 0) ? 1 : 0;  // 1 => int64 encoding
}

// Per-block LDS histogram over buckets (dst >> BKT_BITS).
static __global__ void histA_kernel(const void* __restrict__ ei, const int* __restrict__ flag,
                                    unsigned* __restrict__ histA, int n_edges) {
    __shared__ unsigned h[NBK];
    for (int i = threadIdx.x; i < NBK; i += TPB_A) h[i] = 0u;
    __syncthreads();
    const int is64 = *flag;
    unsigned stride = gridDim.x * blockDim.x;
    for (unsigned e = blockIdx.x * blockDim.x + threadIdx.x; e < (unsigned)n_edges; e += stride) {
        int d = get_dst(ei, is64, n_edges, e);
        atomicAdd(&h[(unsigned)d >> BKT_BITS], 1u);
    }
    __syncthreads();
    for (int i = threadIdx.x; i < NBK; i += TPB_A)
        histA[blockIdx.x * NBK + i] = h[i];
}

// Per bucket slot b: exclusive scan of histA[blk][b] over blk; total[b].
static __global__ void scan1_kernel(unsigned* __restrict__ histA, unsigned* __restrict__ total) {
    __shared__ unsigned s0[NBLKA], s1[NBLKA];
    const int b = blockIdx.x;
    const int t = threadIdx.x;
    unsigned v = histA[t * NBK + b];
    unsigned* a = s0; unsigned* c = s1;
    a[t] = v;
    __syncthreads();
    for (int off = 1; off < NBLKA; off <<= 1) {
        c[t] = a[t] + (t >= off ? a[t - off] : 0u);
        __syncthreads();
        unsigned* tmp = a; a = c; c = tmp;
    }
    histA[t * NBK + b] = a[t] - v;
    if (t == NBLKA - 1) total[b] = a[NBLKA - 1];
}

// Exclusive scan of bucket totals -> bucket_base. One block, NBK threads.
static __global__ void scan2_kernel(const unsigned* __restrict__ total,
                                    unsigned* __restrict__ bucket_base) {
    __shared__ unsigned s0[NBK], s1[NBK];
    const int t = threadIdx.x;
    unsigned v = total[t];
    unsigned* a = s0; unsigned* c = s1;
    a[t] = v;
    __syncthreads();
    for (int off = 1; off < NBK; off <<= 1) {
        c[t] = a[t] + (t >= off ? a[t - off] : 0u);
        __syncthreads();
        unsigned* tmp = a; a = c; c = tmp;
    }
    bucket_base[t] = a[t] - v;
}

// Scatter edges into dst-bucketed order, packed: src | (local_dst << 24).
static __global__ void scatterA_kernel(const void* __restrict__ ei, const int* __restrict__ flag,
                                       const unsigned* __restrict__ histA,
                                       const unsigned* __restrict__ bucket_base,
                                       unsigned* __restrict__ bucketed, int n_edges) {
    __shared__ unsigned cur[NBK];
    for (int i = threadIdx.x; i < NBK; i += TPB_A)
        cur[i] = bucket_base[i] + histA[blockIdx.x * NBK + i];
    __syncthreads();
    const int is64 = *flag;
    unsigned stride = gridDim.x * blockDim.x;
    for (unsigned e = blockIdx.x * blockDim.x + threadIdx.x; e < (unsigned)n_edges; e += stride) {
        unsigned s = (unsigned)get_src(ei, is64, n_edges, e);
        unsigned d = (unsigned)get_dst(ei, is64, n_edges, e);
        unsigned pos = atomicAdd(&cur[d >> BKT_BITS], 1u);
        bucketed[pos] = s | ((d & (BKT_SZ - 1u)) << DST_SHIFT);
    }
}

// Per 256-node bucket: counting sort by local dst; emit csr_src, row_start,
// cnt, dinv AND xs = x*dinv (fused node1). One thread per node.
static __global__ void passB_kernel(const unsigned* __restrict__ bucketed,
                                    const unsigned* __restrict__ total,
                                    const unsigned* __restrict__ bucket_base,
                                    const float* __restrict__ x,
                                    unsigned* __restrict__ csr_src,
                                    unsigned* __restrict__ row_start,
                                    unsigned* __restrict__ cnt,
                                    float* __restrict__ dinv,
                                    float* __restrict__ xs, int n_nodes) {
    const int b = blockIdx.x;
    const int n0 = b << BKT_BITS;
    const int t = threadIdx.x;
    const unsigned base = bucket_base[b];
    const unsigned count = total[b];

    __shared__ unsigned h[BKT_SZ];
    __shared__ unsigned s0[BKT_SZ], s1[BKT_SZ];
    __shared__ unsigned cur[BKT_SZ];
    h[t] = 0u;
    __syncthreads();
    for (unsigned k = t; k < count; k += BKT_SZ)
        atomicAdd(&h[bucketed[base + k] >> DST_SHIFT], 1u);
    __syncthreads();
    unsigned* a = s0; unsigned* c = s1;
    a[t] = h[t];
    __syncthreads();
    for (int off = 1; off < BKT_SZ; off <<= 1) {
        c[t] = a[t] + (t >= off ? a[t - off] : 0u);
        __syncthreads();
        unsigned* tmp = a; a = c; c = tmp;
    }
    // a = inclusive scan; exclusive = a[t]-h[t]
    unsigned excl = a[t] - h[t];
    cur[t] = excl;
    int n = n0 + t;
    if (n < n_nodes) {
        row_start[n] = base + excl;
        cnt[n] = h[t];
        float di = rsqrtf((float)(h[t] + 1u));
        dinv[n] = di;
        float v[12];
#pragma unroll
        for (int j = 0; j < 10; j++) v[j] = x[(size_t)n * 10 + j] * di;
        v[10] = 0.f; v[11] = 0.f;
        float4* xr = (float4*)(xs + (size_t)n * 12);
        xr[0] = make_float4(v[0], v[1], v[2], v[3]);
        xr[1] = make_float4(v[4], v[5], v[6], v[7]);
        xr[2] = make_float4(v[8], v[9], v[10], v[11]);
    }
    __syncthreads();
    for (unsigned k = t; k < count; k += BKT_SZ) {
        unsigned w = bucketed[base + k];
        unsigned pos = base + atomicAdd(&cur[w >> DST_SHIFT], 1u);
        csr_src[pos] = w & SRC_MASK;
    }
}

// Standalone node1 (fallback path only).
static __global__ void node1_kernel(const float* __restrict__ x, const float* __restrict__ dinv,
                                    float* __restrict__ xs, int n_nodes) {
    int i = blockIdx.x * blockDim.x + threadIdx.x;
    if (i >= n_nodes) return;
    float di = dinv[i];
    float v[12];
#pragma unroll
    for (int j = 0; j < 10; j++) v[j] = x[(size_t)i * 10 + j] * di;
    v[10] = 0.f; v[11] = 0.f;
    float4* xr = (float4*)(xs + (size_t)i * 12);
    xr[0] = make_float4(v[0], v[1], v[2], v[3]);
    xr[1] = make_float4(v[4], v[5], v[6], v[7]);
    xr[2] = make_float4(v[8], v[9], v[10], v[11]);
}

// Layer-1 gather + dense 10->16->relu->2 fused (one wave per node).
// Butterfly reduce gives all lanes the aggregate; lanes 0-15 compute one
// hidden unit each; 4-step group reduce; lane 0 writes gs.
static __global__ void gather1_kernel(const unsigned int* __restrict__ row_start,
                                      const unsigned int* __restrict__ cnt,
                                      const unsigned int* __restrict__ csr_src,
                                      const float* __restrict__ xs,
                                      const float* __restrict__ dinv,
                                      const float* __restrict__ W1, const float* __restrict__ b1,
                                      const float* __restrict__ W2,
                                      float* __restrict__ gs, int n_nodes) {
    int w = blockIdx.x * (blockDim.x >> 6) + (threadIdx.x >> 6);
    int lane = threadIdx.x & 63;
    if (w >= n_nodes) return;
    unsigned start = row_start[w];
    unsigned degn = cnt[w];
    float acc[10];
#pragma unroll
    for (int j = 0; j < 10; j++) acc[j] = 0.f;
    const float4* X = (const float4*)xs;
    for (unsigned k = lane; k < degn; k += 64) {
        unsigned s = csr_src[start + k];
        float4 v0 = X[s * 3 + 0];
        float4 v1 = X[s * 3 + 1];
        float4 v2 = X[s * 3 + 2];
        acc[0] += v0.x; acc[1] += v0.y; acc[2] += v0.z; acc[3] += v0.w;
        acc[4] += v1.x; acc[5] += v1.y; acc[6] += v1.z; acc[7] += v1.w;
        acc[8] += v2.x; acc[9] += v2.y;
    }
#pragma unroll
    for (int off = 32; off > 0; off >>= 1) {
#pragma unroll
        for (int j = 0; j < 10; j++) acc[j] += __shfl_xor(acc[j], off);
    }
    float di = dinv[w];
    const float* xsr = xs + (size_t)w * 12;   // self-loop contribution
    float a[10];
#pragma unroll
    for (int j = 0; j < 10; j++) a[j] = (acc[j] + xsr[j]) * di;
    float g0 = 0.f, g1 = 0.f;
    if (lane < 16) {
        float h = b1[lane];
#pragma unroll
        for (int k = 0; k < 10; k++) h = fmaf(a[k], W1[k * 16 + lane], h);
        h = fmaxf(h, 0.f);
        g0 = h * W2[lane * 2 + 0];
        g1 = h * W2[lane * 2 + 1];
    }
#pragma unroll
    for (int off = 8; off > 0; off >>= 1) {
        g0 += __shfl_xor(g0, off);
        g1 += __shfl_xor(g1, off);
    }
    if (lane == 0) {
        gs[(size_t)w * 2 + 0] = g0 * di;
        gs[(size_t)w * 2 + 1] = g1 * di;
    }
}

// Layer-2 gather + final scale + bias, fused.
static __global__ void gather2_kernel(const unsigned int* __restrict__ row_start,
                                      const unsigned int* __restrict__ cnt,
                                      const unsigned int* __restrict__ csr_src,
                                      const float* __restrict__ gs,
                                      const float* __restrict__ dinv,
                                      const float* __restrict__ b2,
                                      float* __restrict__ out, int n_nodes) {
    int w = blockIdx.x * (blockDim.x >> 6) + (threadIdx.x >> 6);
    int lane = threadIdx.x & 63;
    if (w >= n_nodes) return;
    unsigned start = row_start[w];
    unsigned degn = cnt[w];
    float a0 = 0.f, a1 = 0.f;
    const float2* G = (const float2*)gs;
    for (unsigned k = lane; k < degn; k += 64) {
        unsigned s = csr_src[start + k];
        float2 v = G[s];
        a0 += v.x; a1 += v.y;
    }
#pragma unroll
    for (int off = 32; off > 0; off >>= 1) {
        a0 += __shfl_down(a0, off);
        a1 += __shfl_down(a1, off);
    }
    if (lane == 0) {
        float2 self = G[w];
        float di = dinv[w];
        float2 o;
        o.x = fmaf(a0 + self.x, di, b2[0]);
        o.y = fmaf(a1 + self.y, di, b2[1]);
        ((float2*)out)[w] = o;
    }
}

// ---------------- fallback (atomic-CSR build) -------------------------------
static __global__ void deg_kernel(const void* __restrict__ ei, const int* __restrict__ flag,
                                  unsigned int* __restrict__ cnt, int n_edges) {
    const int is64 = *flag;
    unsigned stride = gridDim.x * blockDim.x;
    for (unsigned e = blockIdx.x * blockDim.x + threadIdx.x; e < (unsigned)n_edges; e += stride) {
        int d = get_dst(ei, is64, n_edges, e);
        atomicAdd(&cnt[d], 1u);
    }
}
static __global__ void alloc_kernel(const unsigned int* __restrict__ cnt,
                                    unsigned int* __restrict__ row_start,
                                    unsigned int* __restrict__ cursor,
                                    unsigned int* __restrict__ gcur,
                                    float* __restrict__ dinv, int n_nodes) {
    __shared__ unsigned wsum[4];
    int i = blockIdx.x * blockDim.x + threadIdx.x;
    int lane = threadIdx.x & 63;
    int wid = threadIdx.x >> 6;
    unsigned d = (i < n_nodes) ? cnt[i] : 0u;
    unsigned scan = d;
#pragma unroll
    for (int off = 1; off < 64; off <<= 1) {
        unsigned t = __shfl_up(scan, off);
        if (lane >= off) scan += t;
    }
    if (lane == 63) wsum[wid] = scan;
    __syncthreads();
    if (threadIdx.x == 0) {
        unsigned s0 = wsum[0], s1 = wsum[1], s2 = wsum[2], s3 = wsum[3];
        unsigned base = atomicAdd(gcur, s0 + s1 + s2 + s3);
        wsum[0] = base;
        wsum[1] = base + s0;
        wsum[2] = base + s0 + s1;
        wsum[3] = base + s0 + s1 + s2;
    }
    __syncthreads();
    if (i < n_nodes) {
        unsigned pos = wsum[wid] + scan - d;
        row_start[i] = pos;
        cursor[i] = pos;
        dinv[i] = rsqrtf((float)(d + 1u));
    }
}
static __global__ void csrfill_kernel(const void* __restrict__ ei, const int* __restrict__ flag,
                                      unsigned int* __restrict__ cursor,
                                      unsigned int* __restrict__ csr_src, int n_edges) {
    const int is64 = *flag;
    unsigned stride = gridDim.x * blockDim.x;
    for (unsigned e = blockIdx.x * blockDim.x + threadIdx.x; e < (unsigned)n_edges; e += stride) {
        int s = get_src(ei, is64, n_edges, e);
        int d = get_dst(ei, is64, n_edges, e);
        unsigned pos = atomicAdd(&cursor[d], 1u);
        csr_src[pos] = (unsigned)s;
    }
}

extern "C" void kernel_launch(void* const* d_in, const int* in_sizes, int n_in,
                              void* d_out, int out_size, void* d_ws, size_t ws_size,
                              hipStream_t stream) {
    const float* x  = (const float*)d_in[0];
    const void*  ei = d_in[1];
    const float* W1 = (const float*)d_in[2];
    const float* b1 = (const float*)d_in[3];
    const float* W2 = (const float*)d_in[4];
    const float* b2 = (const float*)d_in[5];
    float* out = (float*)d_out;

    const int n_nodes = in_sizes[0] / 10;
    const int n_edges = in_sizes[1] / 2;
    (void)n_in; (void)out_size;

    const int nbuckets = (n_nodes + BKT_SZ - 1) >> BKT_BITS;
    const bool pack_ok = (n_nodes <= (1 << DST_SHIFT)) && (nbuckets <= NBK);

    char* p = (char*)d_ws;
    int* flag = (int*)p;
    unsigned* gcur = (unsigned*)(p + 64);
    p += 256;
    // common node buffers
    unsigned* row_start = (unsigned*)p; p += (size_t)n_nodes * 4;
    unsigned* cnt = (unsigned*)p;       p += (size_t)n_nodes * 4;
    float* dinv = (float*)p;            p += (size_t)n_nodes * 4;
    float* gs = (float*)p;              p += (size_t)n_nodes * 8;
    float* xs = (float*)p;              p += (size_t)n_nodes * 48;
    unsigned* csr_src = (unsigned*)p;   p += (size_t)n_edges * 4;

    const size_t base_bytes = (size_t)(p - (char*)d_ws);
    const size_t need_new = base_bytes + (size_t)NBLKA * NBK * 4 + 2 * (size_t)NBK * 4 + 64 +
                            (size_t)n_edges * 4;
    const size_t need_old = base_bytes + (size_t)n_nodes * 4;

    if (pack_ok && ws_size >= need_new) {
        unsigned* histA = (unsigned*)p;       p += (size_t)NBLKA * NBK * 4;
        unsigned* total = (unsigned*)p;       p += (size_t)NBK * 4;
        unsigned* bucket_base = (unsigned*)p; p += (size_t)NBK * 4 + 64;
        unsigned* bucketed = (unsigned*)p;    p += (size_t)n_edges * 4;

        detect64_kernel<<<1, 256, 0, stream>>>((const unsigned int*)ei, flag);
        histA_kernel<<<NBLKA, TPB_A, 0, stream>>>(ei, flag, histA, n_edges);
        scan1_kernel<<<NBK, NBLKA, 0, stream>>>(histA, total);
        scan2_kernel<<<1, NBK, 0, stream>>>(total, bucket_base);
        scatterA_kernel<<<NBLKA, TPB_A, 0, stream>>>(ei, flag, histA, bucket_base, bucketed, n_edges);
        passB_kernel<<<nbuckets, BKT_SZ, 0, stream>>>(bucketed, total, bucket_base, x, csr_src,
                                                      row_start, cnt, dinv, xs, n_nodes);
        gather1_kernel<<<(n_nodes + 3) / 4, 256, 0, stream>>>(row_start, cnt, csr_src, xs, dinv,
                                                              W1, b1, W2, gs, n_nodes);
        gather2_kernel<<<(n_nodes + 3) / 4, 256, 0, stream>>>(row_start, cnt, csr_src, gs, dinv,
                                                              b2, out, n_nodes);
    } else if (ws_size >= need_old) {
        unsigned* cursor = (unsigned*)p; p += (size_t)n_nodes * 4;

        hipMemsetAsync(d_ws, 0, 256, stream);
        hipMemsetAsync(cnt, 0, (size_t)n_nodes * 4, stream);
        detect64_kernel<<<1, 256, 0, stream>>>((const unsigned int*)ei, flag);
        deg_kernel<<<2048, 256, 0, stream>>>(ei, flag, cnt, n_edges);
        alloc_kernel<<<(n_nodes + 255) / 256, 256, 0, stream>>>(cnt, row_start, cursor, gcur, dinv, n_nodes);
        csrfill_kernel<<<4096, 256, 0, stream>>>(ei, flag, cursor, csr_src, n_edges);
        node1_kernel<<<(n_nodes + 255) / 256, 256, 0, stream>>>(x, dinv, xs, n_nodes);
        gather1_kernel<<<(n_nodes + 3) / 4, 256, 0, stream>>>(row_start, cnt, csr_src, xs, dinv,
                                                              W1, b1, W2, gs, n_nodes);
        gather2_kernel<<<(n_nodes + 3) / 4, 256, 0, stream>>>(row_start, cnt, csr_src, gs, dinv,
                                                              b2, out, n_nodes);
    }
}

// Round 7
// 216.482 us; speedup vs baseline: 2.9123x; 1.1198x over previous
//
#include <hip/hip_runtime.h>

// ---------------------------------------------------------------------------
// 2-layer GCN: atomic-free CSR build (bucketed counting sort, 256-node
// buckets) + register-accumulating 16-lane-group gathers with fused dense.
//   out = dinv * (A (relu((dinv*(A' xs)) W1 + b1) W2 * dinv)) + b2
// xs = x*dinv, padded to 64B rows (1 cache line per random gather).
// Gathers: 16 lanes per node (4 nodes/wave) -> 4-step xor reduce, dense
// layer = one hidden unit per lane. Edge packed: src | (local_dst << 24).
// ---------------------------------------------------------------------------

#define BKT_BITS  8
#define BKT_SZ    256       // nodes per bucket
#define NBK       512       // padded bucket slots (power of 2, >= n buckets)
#define NBLKA     256       // blocks in histA/scatterA (edge partition)
#define TPB_A     1024      // threads per block in histA/scatterA
#define DST_SHIFT 24
#define SRC_MASK  0xFFFFFFu
#define XS_STRIDE 16        // floats per xs row (64 B)

static __device__ __forceinline__ int get_src(const void* ei, int is64, int n_edges, unsigned e) {
    return is64 ? (int)((const long long*)ei)[e] : ((const int*)ei)[e];
}
static __device__ __forceinline__ int get_dst(const void* ei, int is64, int n_edges, unsigned e) {
    return is64 ? (int)((const long long*)ei)[(unsigned)n_edges + e]
                : ((const int*)ei)[(unsigned)n_edges + e];
}

// Detect whether edge_index arrived as int64 (odd 32-bit words all zero) or int32.
static __global__ void detect64_kernel(const unsigned int* __restrict__ w, int* flag) {
    __shared__ int nz;
    if (threadIdx.x == 0) nz = 0;
    __syncthreads();
    int local = 0;
    for (int k = threadIdx.x; k < 4096; k += blockDim.x)
        if (w[2 * k + 1] != 0u) local = 1;
    if (local) atomicOr(&nz, 1);
    __syncthreads();
    if (threadIdx.x == 0) *flag = (nz == 0) ? 1 : 0;  // 1 => int64 encoding
}

// Per-block LDS histogram over buckets (dst >> BKT_BITS).
static __global__ void histA_kernel(const void* __restrict__ ei, const int* __restrict__ flag,
                                    unsigned* __restrict__ histA, int n_edges) {
    __shared__ unsigned h[NBK];
    for (int i = threadIdx.x; i < NBK; i += TPB_A) h[i] = 0u;
    __syncthreads();
    const int is64 = *flag;
    unsigned stride = gridDim.x * blockDim.x;
    for (unsigned e = blockIdx.x * blockDim.x + threadIdx.x; e < (unsigned)n_edges; e += stride) {
        int d = get_dst(ei, is64, n_edges, e);
        atomicAdd(&h[(unsigned)d >> BKT_BITS], 1u);
    }
    __syncthreads();
    for (int i = threadIdx.x; i < NBK; i += TPB_A)
        histA[blockIdx.x * NBK + i] = h[i];
}

// Per bucket slot b: exclusive scan of histA[blk][b] over blk; total[b].
static __global__ void scan1_kernel(unsigned* __restrict__ histA, unsigned* __restrict__ total) {
    __shared__ unsigned s0[NBLKA], s1[NBLKA];
    const int b = blockIdx.x;
    const int t = threadIdx.x;
    unsigned v = histA[t * NBK + b];
    unsigned* a = s0; unsigned* c = s1;
    a[t] = v;
    __syncthreads();
    for (int off = 1; off < NBLKA; off <<= 1) {
        c[t] = a[t] + (t >= off ? a[t - off] : 0u);
        __syncthreads();
        unsigned* tmp = a; a = c; c = tmp;
    }
    histA[t * NBK + b] = a[t] - v;
    if (t == NBLKA - 1) total[b] = a[NBLKA - 1];
}

// Exclusive scan of bucket totals -> bucket_base. One block, NBK threads.
static __global__ void scan2_kernel(const unsigned* __restrict__ total,
                                    unsigned* __restrict__ bucket_base) {
    __shared__ unsigned s0[NBK], s1[NBK];
    const int t = threadIdx.x;
    unsigned v = total[t];
    unsigned* a = s0; unsigned* c = s1;
    a[t] = v;
    __syncthreads();
    for (int off = 1; off < NBK; off <<= 1) {
        c[t] = a[t] + (t >= off ? a[t - off] : 0u);
        __syncthreads();
        unsigned* tmp = a; a = c; c = tmp;
    }
    bucket_base[t] = a[t] - v;
}

// Scatter edges into dst-bucketed order, packed: src | (local_dst << 24).
static __global__ void scatterA_kernel(const void* __restrict__ ei, const int* __restrict__ flag,
                                       const unsigned* __restrict__ histA,
                                       const unsigned* __restrict__ bucket_base,
                                       unsigned* __restrict__ bucketed, int n_edges) {
    __shared__ unsigned cur[NBK];
    for (int i = threadIdx.x; i < NBK; i += TPB_A)
        cur[i] = bucket_base[i] + histA[blockIdx.x * NBK + i];
    __syncthreads();
    const int is64 = *flag;
    unsigned stride = gridDim.x * blockDim.x;
    for (unsigned e = blockIdx.x * blockDim.x + threadIdx.x; e < (unsigned)n_edges; e += stride) {
        unsigned s = (unsigned)get_src(ei, is64, n_edges, e);
        unsigned d = (unsigned)get_dst(ei, is64, n_edges, e);
        unsigned pos = atomicAdd(&cur[d >> BKT_BITS], 1u);
        bucketed[pos] = s | ((d & (BKT_SZ - 1u)) << DST_SHIFT);
    }
}

// Per 256-node bucket: counting sort by local dst; emit csr_src, row_start,
// cnt, dinv AND xs = x*dinv (fused node1). One thread per node.
static __global__ void passB_kernel(const unsigned* __restrict__ bucketed,
                                    const unsigned* __restrict__ total,
                                    const unsigned* __restrict__ bucket_base,
                                    const float* __restrict__ x,
                                    unsigned* __restrict__ csr_src,
                                    unsigned* __restrict__ row_start,
                                    unsigned* __restrict__ cnt,
                                    float* __restrict__ dinv,
                                    float* __restrict__ xs, int n_nodes) {
    const int b = blockIdx.x;
    const int n0 = b << BKT_BITS;
    const int t = threadIdx.x;
    const unsigned base = bucket_base[b];
    const unsigned count = total[b];

    __shared__ unsigned h[BKT_SZ];
    __shared__ unsigned s0[BKT_SZ], s1[BKT_SZ];
    __shared__ unsigned cur[BKT_SZ];
    h[t] = 0u;
    __syncthreads();
    for (unsigned k = t; k < count; k += BKT_SZ)
        atomicAdd(&h[bucketed[base + k] >> DST_SHIFT], 1u);
    __syncthreads();
    unsigned* a = s0; unsigned* c = s1;
    a[t] = h[t];
    __syncthreads();
    for (int off = 1; off < BKT_SZ; off <<= 1) {
        c[t] = a[t] + (t >= off ? a[t - off] : 0u);
        __syncthreads();
        unsigned* tmp = a; a = c; c = tmp;
    }
    // a = inclusive scan; exclusive = a[t]-h[t]
    unsigned excl = a[t] - h[t];
    cur[t] = excl;
    int n = n0 + t;
    if (n < n_nodes) {
        row_start[n] = base + excl;
        cnt[n] = h[t];
        float di = rsqrtf((float)(h[t] + 1u));
        dinv[n] = di;
        float v[10];
#pragma unroll
        for (int j = 0; j < 10; j++) v[j] = x[(size_t)n * 10 + j] * di;
        float4* xr = (float4*)(xs + (size_t)n * XS_STRIDE);
        xr[0] = make_float4(v[0], v[1], v[2], v[3]);
        xr[1] = make_float4(v[4], v[5], v[6], v[7]);
        xr[2] = make_float4(v[8], v[9], 0.f, 0.f);
        xr[3] = make_float4(0.f, 0.f, 0.f, 0.f);
    }
    __syncthreads();
    for (unsigned k = t; k < count; k += BKT_SZ) {
        unsigned w = bucketed[base + k];
        unsigned pos = base + atomicAdd(&cur[w >> DST_SHIFT], 1u);
        csr_src[pos] = w & SRC_MASK;
    }
}

// Standalone node1 (fallback path only).
static __global__ void node1_kernel(const float* __restrict__ x, const float* __restrict__ dinv,
                                    float* __restrict__ xs, int n_nodes) {
    int i = blockIdx.x * blockDim.x + threadIdx.x;
    if (i >= n_nodes) return;
    float di = dinv[i];
    float v[10];
#pragma unroll
    for (int j = 0; j < 10; j++) v[j] = x[(size_t)i * 10 + j] * di;
    float4* xr = (float4*)(xs + (size_t)i * XS_STRIDE);
    xr[0] = make_float4(v[0], v[1], v[2], v[3]);
    xr[1] = make_float4(v[4], v[5], v[6], v[7]);
    xr[2] = make_float4(v[8], v[9], 0.f, 0.f);
    xr[3] = make_float4(0.f, 0.f, 0.f, 0.f);
}

// Layer-1 gather + dense 10->16->relu->2 fused. 16 lanes per node
// (4 nodes/wave, 16 nodes/block): 4-step xor reduce (stays in group),
// one hidden unit per lane, group reduce of the 2 outputs.
static __global__ void gather1_kernel(const unsigned int* __restrict__ row_start,
                                      const unsigned int* __restrict__ cnt,
                                      const unsigned int* __restrict__ csr_src,
                                      const float* __restrict__ xs,
                                      const float* __restrict__ dinv,
                                      const float* __restrict__ W1, const float* __restrict__ b1,
                                      const float* __restrict__ W2,
                                      float* __restrict__ gs, int n_nodes) {
    __shared__ float sW1[160];
    __shared__ float sb1[16];
    __shared__ float sW2[32];
    for (int k = threadIdx.x; k < 160; k += blockDim.x) sW1[k] = W1[k];
    if (threadIdx.x < 16) sb1[threadIdx.x] = b1[threadIdx.x];
    if (threadIdx.x < 32) sW2[threadIdx.x] = W2[threadIdx.x];
    __syncthreads();
    int node = blockIdx.x * (blockDim.x >> 4) + (threadIdx.x >> 4);
    int lg = threadIdx.x & 15;
    if (node >= n_nodes) return;
    unsigned start = row_start[node];
    unsigned degn = cnt[node];
    float acc[10];
#pragma unroll
    for (int j = 0; j < 10; j++) acc[j] = 0.f;
    const float4* X = (const float4*)xs;
    for (unsigned k = lg; k < degn; k += 16) {
        unsigned s = csr_src[start + k];
        float4 v0 = X[s * 4 + 0];
        float4 v1 = X[s * 4 + 1];
        float4 v2 = X[s * 4 + 2];
        acc[0] += v0.x; acc[1] += v0.y; acc[2] += v0.z; acc[3] += v0.w;
        acc[4] += v1.x; acc[5] += v1.y; acc[6] += v1.z; acc[7] += v1.w;
        acc[8] += v2.x; acc[9] += v2.y;
    }
    if (lg == 0) {   // self-loop contribution (one lane per group; no divergence cost)
        float4 v0 = X[(size_t)node * 4 + 0];
        float4 v1 = X[(size_t)node * 4 + 1];
        float4 v2 = X[(size_t)node * 4 + 2];
        acc[0] += v0.x; acc[1] += v0.y; acc[2] += v0.z; acc[3] += v0.w;
        acc[4] += v1.x; acc[5] += v1.y; acc[6] += v1.z; acc[7] += v1.w;
        acc[8] += v2.x; acc[9] += v2.y;
    }
#pragma unroll
    for (int off = 8; off > 0; off >>= 1) {
#pragma unroll
        for (int j = 0; j < 10; j++) acc[j] += __shfl_xor(acc[j], off);
    }
    float di = dinv[node];
    float h = sb1[lg];
#pragma unroll
    for (int k = 0; k < 10; k++) h = fmaf(acc[k] * di, sW1[k * 16 + lg], h);
    h = fmaxf(h, 0.f);
    float g0 = h * sW2[lg * 2 + 0];
    float g1 = h * sW2[lg * 2 + 1];
#pragma unroll
    for (int off = 8; off > 0; off >>= 1) {
        g0 += __shfl_xor(g0, off);
        g1 += __shfl_xor(g1, off);
    }
    if (lg == 0) {
        float2 o;
        o.x = g0 * di;
        o.y = g1 * di;
        ((float2*)gs)[node] = o;
    }
}

// Layer-2 gather + final scale + bias. 16 lanes per node.
static __global__ void gather2_kernel(const unsigned int* __restrict__ row_start,
                                      const unsigned int* __restrict__ cnt,
                                      const unsigned int* __restrict__ csr_src,
                                      const float* __restrict__ gs,
                                      const float* __restrict__ dinv,
                                      const float* __restrict__ b2,
                                      float* __restrict__ out, int n_nodes) {
    int node = blockIdx.x * (blockDim.x >> 4) + (threadIdx.x >> 4);
    int lg = threadIdx.x & 15;
    if (node >= n_nodes) return;
    unsigned start = row_start[node];
    unsigned degn = cnt[node];
    float a0 = 0.f, a1 = 0.f;
    const float2* G = (const float2*)gs;
    for (unsigned k = lg; k < degn; k += 16) {
        float2 v = G[csr_src[start + k]];
        a0 += v.x; a1 += v.y;
    }
    if (lg == 0) {   // self loop
        float2 s = G[node];
        a0 += s.x; a1 += s.y;
    }
#pragma unroll
    for (int off = 8; off > 0; off >>= 1) {
        a0 += __shfl_xor(a0, off);
        a1 += __shfl_xor(a1, off);
    }
    if (lg == 0) {
        float di = dinv[node];
        float2 o;
        o.x = fmaf(a0, di, b2[0]);
        o.y = fmaf(a1, di, b2[1]);
        ((float2*)out)[node] = o;
    }
}

// ---------------- fallback (atomic-CSR build) -------------------------------
static __global__ void deg_kernel(const void* __restrict__ ei, const int* __restrict__ flag,
                                  unsigned int* __restrict__ cnt, int n_edges) {
    const int is64 = *flag;
    unsigned stride = gridDim.x * blockDim.x;
    for (unsigned e = blockIdx.x * blockDim.x + threadIdx.x; e < (unsigned)n_edges; e += stride) {
        int d = get_dst(ei, is64, n_edges, e);
        atomicAdd(&cnt[d], 1u);
    }
}
static __global__ void alloc_kernel(const unsigned int* __restrict__ cnt,
                                    unsigned int* __restrict__ row_start,
                                    unsigned int* __restrict__ cursor,
                                    unsigned int* __restrict__ gcur,
                                    float* __restrict__ dinv, int n_nodes) {
    __shared__ unsigned wsum[4];
    int i = blockIdx.x * blockDim.x + threadIdx.x;
    int lane = threadIdx.x & 63;
    int wid = threadIdx.x >> 6;
    unsigned d = (i < n_nodes) ? cnt[i] : 0u;
    unsigned scan = d;
#pragma unroll
    for (int off = 1; off < 64; off <<= 1) {
        unsigned t = __shfl_up(scan, off);
        if (lane >= off) scan += t;
    }
    if (lane == 63) wsum[wid] = scan;
    __syncthreads();
    if (threadIdx.x == 0) {
        unsigned s0 = wsum[0], s1 = wsum[1], s2 = wsum[2], s3 = wsum[3];
        unsigned base = atomicAdd(gcur, s0 + s1 + s2 + s3);
        wsum[0] = base;
        wsum[1] = base + s0;
        wsum[2] = base + s0 + s1;
        wsum[3] = base + s0 + s1 + s2;
    }
    __syncthreads();
    if (i < n_nodes) {
        unsigned pos = wsum[wid] + scan - d;
        row_start[i] = pos;
        cursor[i] = pos;
        dinv[i] = rsqrtf((float)(d + 1u));
    }
}
static __global__ void csrfill_kernel(const void* __restrict__ ei, const int* __restrict__ flag,
                                      unsigned int* __restrict__ cursor,
                                      unsigned int* __restrict__ csr_src, int n_edges) {
    const int is64 = *flag;
    unsigned stride = gridDim.x * blockDim.x;
    for (unsigned e = blockIdx.x * blockDim.x + threadIdx.x; e < (unsigned)n_edges; e += stride) {
        int s = get_src(ei, is64, n_edges, e);
        int d = get_dst(ei, is64, n_edges, e);
        unsigned pos = atomicAdd(&cursor[d], 1u);
        csr_src[pos] = (unsigned)s;
    }
}

static inline char* align_up(char* p, size_t a) {
    return (char*)(((uintptr_t)p + a - 1) & ~(uintptr_t)(a - 1));
}

extern "C" void kernel_launch(void* const* d_in, const int* in_sizes, int n_in,
                              void* d_out, int out_size, void* d_ws, size_t ws_size,
                              hipStream_t stream) {
    const float* x  = (const float*)d_in[0];
    const void*  ei = d_in[1];
    const float* W1 = (const float*)d_in[2];
    const float* b1 = (const float*)d_in[3];
    const float* W2 = (const float*)d_in[4];
    const float* b2 = (const float*)d_in[5];
    float* out = (float*)d_out;

    const int n_nodes = in_sizes[0] / 10;
    const int n_edges = in_sizes[1] / 2;
    (void)n_in; (void)out_size;

    const int nbuckets = (n_nodes + BKT_SZ - 1) >> BKT_BITS;
    const bool pack_ok = (n_nodes <= (1 << DST_SHIFT)) && (nbuckets <= NBK);

    char* p = (char*)d_ws;
    int* flag = (int*)p;
    unsigned* gcur = (unsigned*)(p + 64);
    p += 256;
    // common node buffers (each 256B-aligned)
    unsigned* row_start = (unsigned*)p; p = align_up(p + (size_t)n_nodes * 4, 256);
    unsigned* cnt = (unsigned*)p;       p = align_up(p + (size_t)n_nodes * 4, 256);
    float* dinv = (float*)p;            p = align_up(p + (size_t)n_nodes * 4, 256);
    float* gs = (float*)p;              p = align_up(p + (size_t)n_nodes * 8, 256);
    float* xs = (float*)p;              p = align_up(p + (size_t)n_nodes * 4 * XS_STRIDE, 256);
    unsigned* csr_src = (unsigned*)p;   p = align_up(p + (size_t)n_edges * 4, 256);

    const size_t base_bytes = (size_t)(p - (char*)d_ws);
    const size_t need_new = base_bytes + (size_t)NBLKA * NBK * 4 + 2 * (size_t)NBK * 4 + 1024 +
                            (size_t)n_edges * 4;
    const size_t need_old = base_bytes + (size_t)n_nodes * 4 + 256;

    const int NODES_PER_BLK = 256 / 16;  // 16-lane groups, 256-thread blocks
    const int gblocks = (n_nodes + NODES_PER_BLK - 1) / NODES_PER_BLK;

    if (pack_ok && ws_size >= need_new) {
        unsigned* histA = (unsigned*)p;       p = align_up(p + (size_t)NBLKA * NBK * 4, 256);
        unsigned* total = (unsigned*)p;       p = align_up(p + (size_t)NBK * 4, 256);
        unsigned* bucket_base = (unsigned*)p; p = align_up(p + (size_t)NBK * 4, 256);
        unsigned* bucketed = (unsigned*)p;    p = align_up(p + (size_t)n_edges * 4, 256);

        detect64_kernel<<<1, 256, 0, stream>>>((const unsigned int*)ei, flag);
        histA_kernel<<<NBLKA, TPB_A, 0, stream>>>(ei, flag, histA, n_edges);
        scan1_kernel<<<NBK, NBLKA, 0, stream>>>(histA, total);
        scan2_kernel<<<1, NBK, 0, stream>>>(total, bucket_base);
        scatterA_kernel<<<NBLKA, TPB_A, 0, stream>>>(ei, flag, histA, bucket_base, bucketed, n_edges);
        passB_kernel<<<nbuckets, BKT_SZ, 0, stream>>>(bucketed, total, bucket_base, x, csr_src,
                                                      row_start, cnt, dinv, xs, n_nodes);
        gather1_kernel<<<gblocks, 256, 0, stream>>>(row_start, cnt, csr_src, xs, dinv,
                                                    W1, b1, W2, gs, n_nodes);
        gather2_kernel<<<gblocks, 256, 0, stream>>>(row_start, cnt, csr_src, gs, dinv,
                                                    b2, out, n_nodes);
    } else if (ws_size >= need_old) {
        unsigned* cursor = (unsigned*)p;

        hipMemsetAsync(d_ws, 0, 256, stream);
        hipMemsetAsync(cnt, 0, (size_t)n_nodes * 4, stream);
        detect64_kernel<<<1, 256, 0, stream>>>((const unsigned int*)ei, flag);
        deg_kernel<<<2048, 256, 0, stream>>>(ei, flag, cnt, n_edges);
        alloc_kernel<<<(n_nodes + 255) / 256, 256, 0, stream>>>(cnt, row_start, cursor, gcur, dinv, n_nodes);
        csrfill_kernel<<<4096, 256, 0, stream>>>(ei, flag, cursor, csr_src, n_edges);
        node1_kernel<<<(n_nodes + 255) / 256, 256, 0, stream>>>(x, dinv, xs, n_nodes);
        gather1_kernel<<<gblocks, 256, 0, stream>>>(row_start, cnt, csr_src, xs, dinv,
                                                    W1, b1, W2, gs, n_nodes);
        gather2_kernel<<<gblocks, 256, 0, stream>>>(row_start, cnt, csr_src, gs, dinv,
                                                    b2, out, n_nodes);
    }
}